// Round 9
// baseline (685.659 us; speedup 1.0000x reference)
//
#include <hip/hip_runtime.h>
#include <hip/hip_bf16.h>

// Fused masked SDPA: B=64, LQ=LK=1024, D=64, temperature=8.
// R12 = R11 + f16-packed score registers -> launch_bounds(256,4).
// R11 counters: bytes near-minimal (481MB), BW 1.95 TB/s, VALU 20%, MFMA 3%
// -> latency-bound at 33% occupancy. Occupancy is register-bound: sreg[16][4]
// (64 f32) parks in ~64 AGPRs (unified file) + 84 arch VGPRs = 148 combined,
// which fits bounds-3 (170) but not bounds-4 (128) -- that's why R9's
// bounds-4 squeezed to 64+64 and spilled. R9 still hit 2.15 TB/s at 45%
// occupancy WITH the spill tax => occupancy is the lever.
//  - scores packed as f16 pairs (RTNE, 2/u32): sreg 64 -> sp 32 regs.
//    |S|<~8 so f16 err <=~0.003 -> P/AV err ~0.3%; thr ~0.0109, margin ok.
//    L accumulated in f32 before packing; e repacked f16 after exp pass.
//  - launch_bounds(256,4): 4 blocks/CU (16 waves, +33% latency hiding).
//  - everything else byte-identical to R11 (passed determinism): ballot
//    mask->bitmap, unmasked-max one-exp softmax, coalesced K/V private-LDS
//    staging, Pw LDS transpose, hard fence before Ow aliasing writes,
//    staged full-line P f32 epilogue, hw cvt, Q prescaled 1/8.

#define NB   64
#define SLQ  1024
#define SLK  1024
#define DH   64
#define TQ   16
#define TK   64
#define NKT  16
#define KSTR 80    // K slice row stride (u16)
#define VSTR 76    // V slice row stride (u16)
#define PSTR 40    // P bf16 slice row stride (u16)
#define OSTR 68    // O partial row stride (f32)
#define PGSTR 1028 // P f32 stage row stride (f32): +4 pad

typedef __attribute__((ext_vector_type(4))) float          f32x4;
typedef __attribute__((ext_vector_type(8))) __bf16         bf16x8;
typedef __attribute__((ext_vector_type(2))) _Float16       f16x2;
typedef __attribute__((ext_vector_type(8))) unsigned short u16x8;
typedef __attribute__((ext_vector_type(4))) unsigned short u16x4;

static __device__ __forceinline__ unsigned short f2bf(float f) {
  return __builtin_bit_cast(unsigned short, (__bf16)f);   // hw cvt, RTNE
}
static __device__ __forceinline__ bf16x8 cvt8(f32x4 a, f32x4 b) {
  bf16x8 r;
#pragma unroll
  for (int i = 0; i < 4; ++i) { r[i] = (__bf16)a[i]; r[i + 4] = (__bf16)b[i]; }
  return r;
}
static __device__ __forceinline__ u16x4 cvt4(f32x4 v) {
  u16x4 h;
#pragma unroll
  for (int i = 0; i < 4; ++i) h[i] = f2bf(v[i]);
  return h;
}
// f16 pair pack/unpack (RTNE via scalar casts; unpack is exact)
static __device__ __forceinline__ unsigned pk2(float a, float b) {
  unsigned la = __builtin_bit_cast(unsigned short, (_Float16)a);
  unsigned hb = __builtin_bit_cast(unsigned short, (_Float16)b);
  return la | (hb << 16);
}
static __device__ __forceinline__ float lo16(unsigned u) {
  return (float)__builtin_bit_cast(f16x2, u)[0];
}
static __device__ __forceinline__ float hi16(unsigned u) {
  return (float)__builtin_bit_cast(f16x2, u)[1];
}

__global__ __launch_bounds__(256, 4) void sdpa_fused(
    const float* __restrict__ Q, const float* __restrict__ K,
    const float* __restrict__ V, const int* __restrict__ QM,
    const int* __restrict__ KM, const int* __restrict__ MSK,
    float* __restrict__ OUT_AV, float* __restrict__ OUT_P) {
  // XCD swizzle: co-schedule same-batch blocks on one XCD for K/V L2 reuse
  const int g    = blockIdx.x;
  const int slot = g >> 3;
  const int b    = ((slot >> 6) << 3) | (g & 7);
  const int q0   = (slot & 63) * TQ;

  const int tid  = threadIdx.x;
  const int wave = tid >> 6;
  const int lane = tid & 63;
  const int col  = lane & 15;
  const int quad = lane >> 4;
  const int lrow = quad;             // staging row subgroup
  const int lc4  = col * 4;          // staging column (x4 elements)

  // LDS map:
  //  A: [0,19456)      Kw slices (pass1) / Vw slices+Ow partials (pass2)
  //                    / P f32 stage (epilogue)  -- disjoint in time
  //  B: [19456,24576)  P bf16 slices (4 waves x 1280B)
  //  C: [24576,25216)  softmax stats
  //  D: [25216,27328)  mask bitmap u32[16][33] (+1 word row pad)
  __shared__ __align__(16) unsigned char RAW[27328];
  unsigned short* Kw = (unsigned short*)RAW + wave * (16 * KSTR);
  unsigned short* Vw = (unsigned short*)(RAW + wave * (32 * VSTR * 2));
  float*          Ow = (float*)(RAW + wave * (32 * VSTR * 2));
  float*          Pst = (float*)RAW;
  unsigned short* Pw = (unsigned short*)(RAW + 19456) + wave * (16 * PSTR);
  float* partM = (float*)(RAW + 24576);
  float* partL = partM + 64;
  float* rowM  = partL + 64;
  float* rowS  = rowM + 16;
  unsigned* bm = (unsigned*)(RAW + 25216);

  const size_t mbase = ((size_t)b * SLQ + q0) * SLK;
  const f32x4* kb4 = (const f32x4*)(K + (size_t)b * SLK * DH);
  const f32x4* vb4 = (const f32x4*)(V + (size_t)b * SLK * DH);

  // ---- Q A-frags from global, pre-scaled by 1/8 (exact exponent shift) ----
  const float* qp = Q + ((size_t)b * SLQ + q0 + col) * DH + quad * 8;
  bf16x8 aq0, aq1;
  {
    f32x4 a = *(const f32x4*)qp        * 0.125f;
    f32x4 c = *(const f32x4*)(qp + 4)  * 0.125f;
    f32x4 d = *(const f32x4*)(qp + 32) * 0.125f;
    f32x4 e = *(const f32x4*)(qp + 36) * 0.125f;
    aq0 = cvt8(a, c);
    aq1 = cvt8(d, e);
  }

  // ---- K tile 0 prefetch (coalesced full rows), in flight over mask phase -
  f32x4 kreg[4];
#pragma unroll
  for (int j = 0; j < 4; ++j)
    kreg[j] = kb4[(size_t)(wave * 16 + j * 4 + lrow) * 16 + col];

  // ====== mask phase (R9 exact): ballot to bitmap, full-line loads =========
  // key-mask u64 per 64-key chunk (each wave redundantly; KM is 4KB, L2-hot)
  const int* kmB = KM + b * SLK;
  unsigned long long kmb[16];
#pragma unroll
  for (int c = 0; c < 16; ++c)
    kmb[c] = __ballot(kmB[c * 64 + lane] != 0);

  // wave w ballots rows w*4 .. w*4+3; 64 consecutive ints per load (256B)
  const int* mrow = MSK + mbase;
#pragma unroll
  for (int rr = 0; rr < 4; ++rr) {
    const int row = wave * 4 + rr;
    int mv[16];
#pragma unroll
    for (int c = 0; c < 16; ++c)
      mv[c] = mrow[(size_t)row * SLK + c * 64 + lane];
#pragma unroll
    for (int c = 0; c < 16; ++c) {
      unsigned long long mb_ = __ballot(mv[c] != 0) & kmb[c];
      if (lane < 2) bm[row * 33 + c * 2 + lane] = (unsigned)(mb_ >> (lane * 32));
    }
  }
  __syncthreads();   // bitmap visible to all waves

  // ========= Pass 1 (barrier-free): S = (Q/8)K^T, packed f16 scores ========
  unsigned sp[NKT][2];   // sp[kt][0]=(r0,r1) sp[kt][1]=(r2,r3), f16 pairs
#pragma unroll
  for (int kt = 0; kt < NKT; ++kt) {
    // stage this wave's 16 K rows into its private slice
#pragma unroll
    for (int j = 0; j < 4; ++j)
      *(u16x4*)&Kw[(j * 4 + lrow) * KSTR + lc4] = cvt4(kreg[j]);

    // prefetch tile kt+1 (coalesced full rows)
    if (kt < NKT - 1) {
      const int brow = (kt + 1) * TK + wave * 16;
#pragma unroll
      for (int j = 0; j < 4; ++j)
        kreg[j] = kb4[(size_t)(brow + j * 4 + lrow) * 16 + col];
    }

    // B-frag: K[key = wave*16+col][k = quad*8+j (+32)]
    bf16x8 bk0 = __builtin_bit_cast(bf16x8, *(const u16x8*)&Kw[col * KSTR + quad * 8]);
    bf16x8 bk1 = __builtin_bit_cast(bf16x8, *(const u16x8*)&Kw[col * KSTR + quad * 8 + 32]);
    f32x4 acc = {0.f, 0.f, 0.f, 0.f};
    acc = __builtin_amdgcn_mfma_f32_16x16x32_bf16(aq0, bk0, acc, 0, 0, 0);
    acc = __builtin_amdgcn_mfma_f32_16x16x32_bf16(aq1, bk1, acc, 0, 0, 0);
    sp[kt][0] = pk2(acc[0], acc[1]);   // raw unmasked scores, f16 RTNE
    sp[kt][1] = pk2(acc[2], acc[3]);
  }

  // prefetch V step 0 (2 tiles x this wave's 16 rows) during stats phase
  f32x4 vreg[8];
#pragma unroll
  for (int j = 0; j < 8; ++j)
    vreg[j] = vb4[(size_t)((j >> 2) * TK + wave * 16 + (j & 3) * 4 + lrow) * 16 + col];

  // ---- gather this lane's 64 mask bits from the bitmap -------------------
  const int sh = (wave & 1) * 16 + col;
  const int wh = wave >> 1;
  unsigned mbits0 = 0u, mbits1 = 0u;   // bit (kt&7)*4+r of mbits[kt>>3]
#pragma unroll
  for (int kt = 0; kt < NKT; ++kt)
#pragma unroll
    for (int r = 0; r < 4; ++r) {
      unsigned bit = (bm[(quad * 4 + r) * 33 + kt * 2 + wh] >> sh) & 1u;
      if (kt < 8) mbits0 |= bit << ((kt & 7) * 4 + r);
      else        mbits1 |= bit << ((kt & 7) * 4 + r);
    }

  // ====== stats: unmasked max -> butterfly -> masked exp pass -> sum =======
  float Mw[4], Cr[4];
#pragma unroll
  for (int r = 0; r < 4; ++r) {
    float m = (r & 1) ? hi16(sp[0][r >> 1]) : lo16(sp[0][r >> 1]);
#pragma unroll
    for (int kt = 1; kt < NKT; ++kt) {
      float s = (r & 1) ? hi16(sp[kt][r >> 1]) : lo16(sp[kt][r >> 1]);
      m = fmaxf(m, s);
    }
#pragma unroll
    for (int off = 1; off < 16; off <<= 1) m = fmaxf(m, __shfl_xor(m, off, 64));
    Mw[r] = m;
  }
  // masked exp over pairs; e repacked f16 (e in [0,1], exact-enough)
  float lv[4] = {0.f, 0.f, 0.f, 0.f};
#pragma unroll
  for (int rp = 0; rp < 2; ++rp) {
    const int r0 = rp * 2, r1 = rp * 2 + 1;
#pragma unroll
    for (int kt = 0; kt < NKT; ++kt) {
      float e0 = __expf(lo16(sp[kt][rp]) - Mw[r0]);
      float e1 = __expf(hi16(sp[kt][rp]) - Mw[r1]);
      const unsigned mb = (kt < 8) ? mbits0 : mbits1;
      e0 = ((mb >> ((kt & 7) * 4 + r0)) & 1u) ? e0 : 0.f;
      e1 = ((mb >> ((kt & 7) * 4 + r1)) & 1u) ? e1 : 0.f;
      lv[r0] += e0;
      lv[r1] += e1;
      sp[kt][rp] = pk2(e0, e1);        // reuse in pass 2/epilogue: p = e*Cr
    }
  }
#pragma unroll
  for (int r = 0; r < 4; ++r) {
    float l = lv[r];
#pragma unroll
    for (int off = 1; off < 16; off <<= 1) l += __shfl_xor(l, off, 64);
    if (col == 0) {
      partM[wave * 16 + quad * 4 + r] = Mw[r];
      partL[wave * 16 + quad * 4 + r] = l;
    }
  }
  __syncthreads();
  if (tid < TQ) {
    float M = -INFINITY, L = 0.f;
#pragma unroll
    for (int w = 0; w < 4; ++w) {
      float m_ = partM[w * 16 + tid], l_ = partL[w * 16 + tid];
      float mn = fmaxf(M, m_);
      L = L * __expf(M - mn) + l_ * __expf(m_ - mn);  // finite inputs
      M = mn;
    }
    rowM[tid] = M;
    rowS[tid] = (QM[b * SLQ + q0 + tid] && L > 0.f) ? (1.f / L) : 0.f;
  }
  __syncthreads();
#pragma unroll
  for (int r = 0; r < 4; ++r)
    Cr[r] = __expf(Mw[r] - rowM[quad * 4 + r]) * rowS[quad * 4 + r];

  // ====== Pass 2 (barrier-free): 8 steps of 2 tiles, V via private LDS =====
  f32x4 acco[4] = {{0.f,0.f,0.f,0.f},{0.f,0.f,0.f,0.f},
                   {0.f,0.f,0.f,0.f},{0.f,0.f,0.f,0.f}};
#pragma unroll
  for (int st = 0; st < 8; ++st) {
    const int kt0 = st * 2, kt1 = kt0 + 1;
    // stage V rows (32: tile kt0 then kt1) into private slice
#pragma unroll
    for (int j = 0; j < 8; ++j)
      *(u16x4*)&Vw[(j * 4 + lrow) * VSTR + lc4] = cvt4(vreg[j]);

    // p = e*Cr into bf16 transpose slice (e unpacked f16->f32, exact)
#pragma unroll
    for (int r = 0; r < 4; ++r) {
      float e0 = (r & 1) ? hi16(sp[kt0][r >> 1]) : lo16(sp[kt0][r >> 1]);
      float e1 = (r & 1) ? hi16(sp[kt1][r >> 1]) : lo16(sp[kt1][r >> 1]);
      Pw[(quad * 4 + r) * PSTR + col]      = f2bf(e0 * Cr[r]);
      Pw[(quad * 4 + r) * PSTR + 16 + col] = f2bf(e1 * Cr[r]);
    }

    // prefetch next step's V
    if (st < 7) {
#pragma unroll
      for (int j = 0; j < 8; ++j)
        vreg[j] = vb4[(size_t)((st * 2 + 2 + (j >> 2)) * TK + wave * 16 + (j & 3) * 4 + lrow) * 16
                      + col];
    }

    // A = P[q=col][kk=quad*8+j]; B = V[kk=quad*8+j][d=n0*16+col]
    bf16x8 ap = __builtin_bit_cast(bf16x8, *(const u16x8*)&Pw[col * PSTR + quad * 8]);
#pragma unroll
    for (int n0 = 0; n0 < 4; ++n0) {
      u16x8 rv;
#pragma unroll
      for (int j = 0; j < 8; ++j)
        rv[j] = Vw[(quad * 8 + j) * VSTR + n0 * 16 + col];
      acco[n0] = __builtin_amdgcn_mfma_f32_16x16x32_bf16(
          ap, __builtin_bit_cast(bf16x8, rv), acco[n0], 0, 0, 0);
    }
  }

  // ====== final O: per-wave partial -> LDS -> cross-wave reduce ============
  // HARD FENCE: Ow (f32) aliases Vw/Pw-read bytes (u16). TBAA lets the
  // scheduler move the f32 stores above the u16 reads without this barrier
  // (compiler memory fence + wave sync) -- the R10 nondeterminism.
  __syncthreads();
#pragma unroll
  for (int n0 = 0; n0 < 4; ++n0)
#pragma unroll
    for (int r = 0; r < 4; ++r)
      Ow[(quad * 4 + r) * OSTR + n0 * 16 + col] = acco[n0][r];
  __syncthreads();
  {
    const int qq = tid >> 4, dd = (tid & 15) * 4;
    f32x4 s = {0.f, 0.f, 0.f, 0.f};
#pragma unroll
    for (int w = 0; w < 4; ++w) {
      const float* Os = (const float*)(RAW + w * (32 * VSTR * 2));
      s += *(const f32x4*)&Os[qq * OSTR + dd];
    }
    *(f32x4*)&OUT_AV[((size_t)b * SLQ + q0 + qq) * DH + dd] = s;
  }
  __syncthreads();   // region A now free for P staging

  // ====== P f32 output: stage 4-row chunks, drain contiguous rows ==========
#pragma unroll
  for (int c = 0; c < 4; ++c) {
    if (quad == c) {
#pragma unroll
      for (int kt = 0; kt < NKT; ++kt)
#pragma unroll
        for (int r = 0; r < 4; ++r) {
          float e = (r & 1) ? hi16(sp[kt][r >> 1]) : lo16(sp[kt][r >> 1]);
          Pst[r * PGSTR + kt * TK + wave * 16 + col] = e * Cr[r];
        }
    }
    __syncthreads();
    {
      float* dst = OUT_P + mbase + (size_t)(c * 4) * SLK;
#pragma unroll
      for (int i = 0; i < 4; ++i)
        *(f32x4*)&dst[(size_t)i * SLK + tid * 4] =
            *(const f32x4*)&Pst[i * PGSTR + tid * 4];
    }
    if (c < 3) __syncthreads();
  }
}

extern "C" void kernel_launch(void* const* d_in, const int* in_sizes, int n_in,
                              void* d_out, int out_size, void* d_ws, size_t ws_size,
                              hipStream_t stream) {
  const float* q  = (const float*)d_in[0];
  const float* k  = (const float*)d_in[1];
  const float* v  = (const float*)d_in[2];
  const int*   qm = (const int*)d_in[3];
  const int*   km = (const int*)d_in[4];
  const int*   mk = (const int*)d_in[5];
  float* out_av = (float*)d_out;                          // [B,LQ,D]
  float* out_p  = out_av + (size_t)NB * SLQ * DH;         // [B,LQ,LK]
  sdpa_fused<<<dim3(NB * (SLQ / TQ)), dim3(256), 0, stream>>>(q, k, v, qm, km, mk, out_av, out_p);
}